// Round 12
// baseline (216.470 us; speedup 1.0000x reference)
//
#include <hip/hip_runtime.h>
#include <hip/hip_fp16.h>

#define NEG_SLOPE 0.2f
#define BN_EPS 1e-5f

constexpr int D = 64;   // feature dim
constexpr int H = 4;    // heads

// ---- direct-CSR counting sort geometry ----
// Per-node u16 counters packed 2-per-u32 in LDS. Edge partitions are pow2
// chunks so p = e>>CHUNK_SHIFT (no div). Per-partition per-node count <=
// CHUNK = 16384 < 65536 -> no u16 carry.
constexpr int PSORT = 64;                  // edge partitions
constexpr int CHUNK_SHIFT = 14;            // 16384 edges/partition
constexpr int CHUNK = 1 << CHUNK_SHIFT;    // covers E <= 1,048,576
constexpr int NGROUPS = 4;                 // node groups (hist blocks per p)
constexpr int MAXWG = 6272;                // packed words per group -> N <= 50176
constexpr int BN_SLICES = 32;              // BN stat privatization

typedef _Float16 half2_t __attribute__((ext_vector_type(2)));
typedef _Float16 half4_t __attribute__((ext_vector_type(4)));
typedef _Float16 half8_t __attribute__((ext_vector_type(8)));
typedef float f32x4_t __attribute__((ext_vector_type(4)));
typedef int i32x4 __attribute__((ext_vector_type(4)));  // native vec for nontemporal builtins

// 16-B edge record: {src, pad, w[4]}; w = per-edge softmax numerators (4 heads)
union Rec {
    i32x4 i4;
    struct { int idx; int pad; half4_t w; } f;
};

#define MFMA16(a, b, c) __builtin_amdgcn_mfma_f32_16x16x32_f16(a, b, c, 0, 0, 0)

#if __has_builtin(__builtin_amdgcn_fdot2)
#define FDOT2(a, b, c) __builtin_amdgcn_fdot2((a), (b), (c), false)
#else
#define FDOT2(a, b, c) ((c) + (float)(a)[0] * (float)(b)[0] + (float)(a)[1] * (float)(b)[1])
#endif

__device__ inline half2_t h2cast(unsigned int u) { return __builtin_bit_cast(half2_t, u); }

__device__ inline float lrelu(float v) { return (v >= 0.f) ? v : NEG_SLOPE * v; }

// load 8 consecutive fp32, split into fp16 hi + lo halves (hi+lo ~ fp32)
__device__ inline void split8(const float* p, bool ok, half8_t& hi, half8_t& lo) {
    float f[8];
    if (ok) {
        float4 a = *(const float4*)p;
        float4 b = *(const float4*)(p + 4);
        f[0] = a.x; f[1] = a.y; f[2] = a.z; f[3] = a.w;
        f[4] = b.x; f[5] = b.y; f[6] = b.z; f[7] = b.w;
    } else {
        #pragma unroll
        for (int j = 0; j < 8; j++) f[j] = 0.f;
    }
    #pragma unroll
    for (int j = 0; j < 8; j++) {
        _Float16 h = (_Float16)f[j];
        hi[j] = h;
        lo[j] = (_Float16)(f[j] - (float)h);
    }
}

// R12: one-time weight pre-split. Every GEMM wave was recomputing split8 on
// the (constant) weights: 10 split8 ~ 320 VALU per wave x 6252 waves.
// Precompute packed hi/lo fp16 tables once (bit-identical split semantics);
// GEMM waves then do plain 16-B half8 loads (half the weight bytes, zero
// cvt VALU). 64 blocks, trivial.
__global__ __launch_bounds__(256) void k_prep(
    const float* __restrict__ W_lin, const float* __restrict__ W_gat,
    _Float16* __restrict__ wlin_hi, _Float16* __restrict__ wlin_lo,
    _Float16* __restrict__ wgat_hi, _Float16* __restrict__ wgat_lo)
{
    const int i = blockIdx.x * 256 + threadIdx.x;
    if (i < 64 * 64) {
        float v = W_lin[i];
        _Float16 h = (_Float16)v;
        wlin_hi[i] = h;
        wlin_lo[i] = (_Float16)(v - (float)h);
    }
    if (i < 256 * 64) {
        float v = W_gat[i];
        _Float16 h = (_Float16)v;
        wgat_hi[i] = h;
        wgat_lo[i] = (_Float16)(v - (float)h);
    }
}

// UNIFIED node-GEMM + histogram kernel. Hist blocks FIRST (R11: 256 blocks
// at 1-2/CU co-reside with GEMM; GEMM-first serialized the roles).
//   blocks [0, NBH):        per-(partition p, node-group g) packed-u16 LDS
//                           histogram; emits gcnt[p][*] + rank[e]; block 0
//                           zeroes gcount.
//   blocks [NBH, NBH+NB1):  32-node MFMA GEMM
__global__ __launch_bounds__(256) void k_nodehist(
    const float* __restrict__ x,
    const _Float16* __restrict__ wlin_hi, const _Float16* __restrict__ wlin_lo,
    const float* __restrict__ b_lin,
    const float* __restrict__ prelu_w,
    const _Float16* __restrict__ wgat_hi, const _Float16* __restrict__ wgat_lo,
    const float* __restrict__ att_src, const float* __restrict__ att_dst,
    _Float16* __restrict__ hh, float* __restrict__ asrc_ws,
    float* __restrict__ adst_ws, const int* __restrict__ ei,
    unsigned int* __restrict__ gcnt, int* __restrict__ rank,
    int* __restrict__ gcount, int N, int E, int NBH, int NG, int WTOT)
{
    __shared__ unsigned int smem4[MAXWG];  // 25.1 KB shared by both roles
    const int t = threadIdx.x;

    if ((int)blockIdx.x < NBH) {
        // ---------------- histogram role ----------------
        unsigned int* cnt = smem4;
        const int hb = blockIdx.x;
        const int p = hb & (PSORT - 1);
        const int g = hb >> 6;             // node group 0..3 (PSORT=64)
        const int Wg = NG >> 1;            // packed words per group
        for (int i = t; i < Wg; i += 256) cnt[i] = 0;
        __syncthreads();
        const int e0 = p << CHUNK_SHIFT;
        const int e1 = min(E, e0 + CHUNK);
        const int nlo = g * NG;
        for (int e = e0 + t; e < e1; e += 256) {
            int dl = ei[E + e] - nlo;
            if ((unsigned)dl < (unsigned)NG) {
                const unsigned int sh = (unsigned)(dl & 1) * 16;
                unsigned int old = atomicAdd(&cnt[dl >> 1], 1u << sh);
                rank[e] = (int)((old >> sh) & 0xffffu);
            }
        }
        __syncthreads();
        unsigned int* dst = gcnt + (size_t)p * WTOT + (size_t)g * Wg;
        for (int i = t; i < Wg; i += 256) dst[i] = cnt[i];
        if (hb == 0 && t == 0) gcount[0] = 0;   // stream-ordered before k_off
        return;
    }

    // ---------------- node GEMM role ----------------
    _Float16* smem = (_Float16*)smem4;
    _Float16* __restrict__ h_lds = smem;           // [32][264] after re-barrier
    _Float16* __restrict__ x1hi  = smem;           // [32][72]
    _Float16* __restrict__ x1lo  = smem + 32 * 72; // [32][72]

    const int w = t >> 6;    // wave id == head
    const int l = t & 63;
    const int li = l & 15;
    const int lq = l >> 4;
    const int base = (blockIdx.x - NBH) * 32;
    const int nvalid = min(32, N - base);

    // ---- stage A: MFMA x @ W_lin^T for cols 16w..16w+15, 2 m-tiles ----
    f32x4_t accA[2] = {};
    {
        half8_t blh[2], bll[2];
        const int n = 16 * w + li;
        #pragma unroll
        for (int ks = 0; ks < 2; ks++) {
            const int off = n * 64 + 32 * ks + 8 * lq;
            blh[ks] = *(const half8_t*)(wlin_hi + off);
            bll[ks] = *(const half8_t*)(wlin_lo + off);
        }
        #pragma unroll
        for (int mt = 0; mt < 2; mt++) {
            const int row = base + 16 * mt + li;
            const bool ok = row < N;
            #pragma unroll
            for (int ks = 0; ks < 2; ks++) {
                half8_t ah, al;
                split8(x + (size_t)row * 64 + 32 * ks + 8 * lq, ok, ah, al);
                accA[mt] = MFMA16(ah, blh[ks], accA[mt]);
                accA[mt] = MFMA16(al, blh[ks], accA[mt]);
                accA[mt] = MFMA16(ah, bll[ks], accA[mt]);
            }
        }
    }

    // epilogue A: +bias, prelu, split to fp16 hi/lo in LDS
    {
        const int n = 16 * w + li;
        const float bl = b_lin[n];
        const float pw = prelu_w[n];
        #pragma unroll
        for (int mt = 0; mt < 2; mt++) {
            #pragma unroll
            for (int r = 0; r < 4; r++) {
                const int m = 16 * mt + lq * 4 + r;
                float v = accA[mt][r] + bl;
                v = (v >= 0.f) ? v : pw * v;
                _Float16 hi = (_Float16)v;
                x1hi[m * 72 + n] = hi;
                x1lo[m * 72 + n] = (_Float16)(v - (float)hi);
            }
        }
    }
    __syncthreads();

    // ---- stage B: MFMA x1 @ W_gat^T for cols 64w..64w+63, 2 m-tiles ----
    half8_t xah[2][2], xal[2][2];
    #pragma unroll
    for (int mt = 0; mt < 2; mt++) {
        #pragma unroll
        for (int ks = 0; ks < 2; ks++) {
            const int off = (16 * mt + li) * 72 + 32 * ks + 8 * lq;
            xah[mt][ks] = *(const half8_t*)(&x1hi[off]);
            xal[mt][ks] = *(const half8_t*)(&x1lo[off]);
        }
    }
    f32x4_t accB[2][4] = {};
    #pragma unroll
    for (int nt = 0; nt < 4; nt++) {
        half8_t wh[2], wl[2];
        const int c = 64 * w + 16 * nt + li;
        #pragma unroll
        for (int ks = 0; ks < 2; ks++) {
            const int off = c * 64 + 32 * ks + 8 * lq;
            wh[ks] = *(const half8_t*)(wgat_hi + off);
            wl[ks] = *(const half8_t*)(wgat_lo + off);
        }
        #pragma unroll
        for (int mt = 0; mt < 2; mt++) {
            #pragma unroll
            for (int ks = 0; ks < 2; ks++) {
                accB[mt][nt] = MFMA16(xah[mt][ks], wh[ks], accB[mt][nt]);
                accB[mt][nt] = MFMA16(xal[mt][ks], wh[ks], accB[mt][nt]);
                accB[mt][nt] = MFMA16(xah[mt][ks], wl[ks], accB[mt][nt]);
            }
        }
    }

    // ---- attention dots from registers: a[n][w] = sum_d h[n][w][d]*att[w][d]
    {
        float asv[4], adv[4];
        #pragma unroll
        for (int nt = 0; nt < 4; nt++) {
            const int c = 64 * w + 16 * nt + li;
            asv[nt] = att_src[c];
            adv[nt] = att_dst[c];
        }
        #pragma unroll
        for (int mt = 0; mt < 2; mt++) {
            #pragma unroll
            for (int r = 0; r < 4; r++) {
                float s = 0.f, dsum = 0.f;
                #pragma unroll
                for (int nt = 0; nt < 4; nt++) {
                    s += accB[mt][nt][r] * asv[nt];
                    dsum += accB[mt][nt][r] * adv[nt];
                }
                #pragma unroll
                for (int off = 1; off < 16; off <<= 1) {
                    s += __shfl_xor(s, off, 64);
                    dsum += __shfl_xor(dsum, off, 64);
                }
                if (li == 0) {
                    const int m = 16 * mt + lq * 4 + r;
                    if (m < nvalid) {
                        asrc_ws[(size_t)(base + m) * H + w] = s;
                        adst_ws[(size_t)(base + m) * H + w] = dsum;
                    }
                }
            }
        }
    }

    // WAR guard: all waves must finish their x1 ds_reads before h_lds
    // (same LDS bytes) is overwritten.
    __syncthreads();

    // ---- h -> LDS in padded [m][264] layout, then coalesced global write ----
    #pragma unroll
    for (int mt = 0; mt < 2; mt++) {
        #pragma unroll
        for (int nt = 0; nt < 4; nt++) {
            #pragma unroll
            for (int r = 0; r < 4; r++) {
                const int m = 16 * mt + lq * 4 + r;
                const int d = 16 * nt + li;
                h_lds[m * 264 + d * 4 + w] = (_Float16)accB[mt][nt][r];
            }
        }
    }
    __syncthreads();
    {
        const int chunks = nvalid * 32;  // 8 halves (16B) per chunk
        const uint4* src = (const uint4*)h_lds;
        uint4* dst = (uint4*)(hh + (size_t)base * 256);
        for (int i = t; i < chunks; i += 256) {
            int row = i >> 5;
            int col = i & 31;
            dst[i] = src[row * 33 + col];  // padded row = 33 uint4
        }
    }
}

// Pass 2: one thread per node PAIR, column-walk over the PSORT partials with
// 32-wide batched prefetch (R7: the serial walk was a ~45us latency chain).
// PSORT=64 -> 2 rounds. Block 0 also zeroes the BN sums slices.
__global__ __launch_bounds__(256) void k_off(unsigned int* __restrict__ gcnt,
                                             int* __restrict__ gcount,
                                             int* __restrict__ offs,
                                             int* __restrict__ deg,
                                             float* __restrict__ sums,
                                             int N, int WTOT) {
    if (blockIdx.x == 0) {
        for (int j = threadIdx.x; j < BN_SLICES * 128; j += 256) sums[j] = 0.f;
    }
    __shared__ int sm[256];
    __shared__ int sbase;
    const int t = threadIdx.x;
    const int i = blockIdx.x * 256 + t;      // pair index
    int d0 = 0, d1 = 0;
    if (i < WTOT) {
        unsigned int run = 0;                // packed running prefix
        for (int pb = 0; pb < PSORT; pb += 32) {
            unsigned int c[32];
            #pragma unroll
            for (int j = 0; j < 32; j++)
                c[j] = gcnt[(size_t)(pb + j) * WTOT + i];
            #pragma unroll
            for (int j = 0; j < 32; j++) {
                unsigned int cc = c[j];
                gcnt[(size_t)(pb + j) * WTOT + i] = run;
                run += cc;
            }
        }
        d0 = (int)(run & 0xffffu);
        d1 = (int)(run >> 16);
    }
    int v = d0 + d1;
    sm[t] = v;
    __syncthreads();
    for (int off = 1; off < 256; off <<= 1) {
        int u = (t >= off) ? sm[t - off] : 0;
        __syncthreads();
        sm[t] += u;
        __syncthreads();
    }
    if (t == 255) sbase = atomicAdd(gcount, sm[255]);
    __syncthreads();
    const int base = sbase + sm[t] - v;
    const int n0 = 2 * i;
    if (n0 < N)     { offs[n0] = base;          deg[n0] = d0; }
    if (n0 + 1 < N) { offs[n0 + 1] = base + d0; deg[n0 + 1] = d1; }
}

// Pass 3: single full-occupancy per-edge pass:
// pos = offs[d] + pref[p][d] + rank[e]; one NT 16-B store per rec.
__global__ __launch_bounds__(256) void k_fill(const int* __restrict__ ei,
                                              const unsigned int* __restrict__ gcnt,
                                              const int* __restrict__ offs,
                                              const int* __restrict__ rank,
                                              const float* __restrict__ asrc,
                                              const float* __restrict__ adst,
                                              i32x4* __restrict__ recs,
                                              int E, int WTOT) {
    int e = blockIdx.x * 256 + threadIdx.x;
    if (e >= E) return;
    int s = ei[e];
    int d = ei[E + e];
    int p = e >> CHUNK_SHIFT;
    const unsigned int sh = (unsigned)(d & 1) * 16;
    int pr = (int)((gcnt[(size_t)p * WTOT + (d >> 1)] >> sh) & 0xffffu);
    int pos = offs[d] + pr + rank[e];
    float4 a = *(const float4*)(asrc + (size_t)s * H);
    float4 b = *(const float4*)(adst + (size_t)d * H);
    Rec r;
    r.f.idx = s;
    r.f.pad = 0;
    r.f.w[0] = (_Float16)__expf(lrelu(a.x + b.x));
    r.f.w[1] = (_Float16)__expf(lrelu(a.y + b.y));
    r.f.w[2] = (_Float16)__expf(lrelu(a.z + b.z));
    r.f.w[3] = (_Float16)__expf(lrelu(a.w + b.w));
    __builtin_nontemporal_store(r.i4, recs + pos);
}

// process one edge pair (A,B) with packed fp16 math.
__device__ inline void edge_pair(const i32x4 ra, const i32x4 rb,
                                 const uint2 ha, const uint2 hb,
                                 float& den0, float& den1, float& den2, float& den3,
                                 float& acc0, float& acc1, float& acc2, float& acc3)
{
    const half2_t one2 = h2cast(0x3C003C00u);
    unsigned int wp0 = __builtin_amdgcn_perm((unsigned int)rb.z, (unsigned int)ra.z, 0x05040100u);
    unsigned int wp1 = __builtin_amdgcn_perm((unsigned int)rb.z, (unsigned int)ra.z, 0x07060302u);
    unsigned int wp2 = __builtin_amdgcn_perm((unsigned int)rb.w, (unsigned int)ra.w, 0x05040100u);
    unsigned int wp3 = __builtin_amdgcn_perm((unsigned int)rb.w, (unsigned int)ra.w, 0x07060302u);
    unsigned int hp0 = __builtin_amdgcn_perm(hb.x, ha.x, 0x05040100u);
    unsigned int hp1 = __builtin_amdgcn_perm(hb.x, ha.x, 0x07060302u);
    unsigned int hp2 = __builtin_amdgcn_perm(hb.y, ha.y, 0x05040100u);
    unsigned int hp3 = __builtin_amdgcn_perm(hb.y, ha.y, 0x07060302u);
    den0 = FDOT2(h2cast(wp0), one2, den0);
    den1 = FDOT2(h2cast(wp1), one2, den1);
    den2 = FDOT2(h2cast(wp2), one2, den2);
    den3 = FDOT2(h2cast(wp3), one2, den3);
    acc0 = FDOT2(h2cast(wp0), h2cast(hp0), acc0);
    acc1 = FDOT2(h2cast(wp1), h2cast(hp1), acc1);
    acc2 = FDOT2(h2cast(wp2), h2cast(hp2), acc2);
    acc3 = FDOT2(h2cast(wp3), h2cast(hp3), acc3);
}

// ---- fused softmax + aggregation + BN partial stats ----
// One node per wave (R9 geometry: 12500 blocks, occupancy ~70%, ~59.5us —
// at the random-gather fabric floor; FETCH 198MB ~ 8 XCD x hh re-fetch).
// BN: block-level LDS reduction then 128 atomics/block onto 32-way-sliced
// sums. Barrier-safe: invalid waves contribute zeros.
__global__ __launch_bounds__(256) void k_agg(
    const float* __restrict__ asrc, const float* __restrict__ adst,
    const int* __restrict__ offs, const int* __restrict__ deg,
    const i32x4* __restrict__ recs, const uint2* __restrict__ hh2,
    float* __restrict__ out, float* __restrict__ sums, int N)
{
    const int t = threadIdx.x;
    const int w = t >> 6;
    const int lane = t & 63;
    const int i = blockIdx.x * 4 + w;      // one node per wave

    float sAcc = 0.f, qAcc = 0.f;
    if (i < N) {
        float4 b = *(const float4*)(adst + (size_t)i * H);
        float4 a0 = *(const float4*)(asrc + (size_t)i * H);
        float ws0 = __expf(lrelu(a0.x + b.x));
        float ws1 = __expf(lrelu(a0.y + b.y));
        float ws2 = __expf(lrelu(a0.z + b.z));
        float ws3 = __expf(lrelu(a0.w + b.w));

        const int beg = __builtin_amdgcn_readfirstlane(offs[i]);
        const int dg  = __builtin_amdgcn_readfirstlane(deg[i]);

        // self-loop contribution
        float den0 = ws0, den1 = ws1, den2 = ws2, den3 = ws3;
        float acc0, acc1, acc2, acc3;
        {
            uint2 hv = hh2[(size_t)i * D + lane];
            half2_t s01 = h2cast(hv.x), s23 = h2cast(hv.y);
            acc0 = ws0 * (float)s01[0];
            acc1 = ws1 * (float)s01[1];
            acc2 = ws2 * (float)s23[0];
            acc3 = ws3 * (float)s23[1];
        }

        const int nfull = dg & ~7;
        int k = 0;
        for (; k < nfull; k += 8) {
            i32x4 rr[8];
            #pragma unroll
            for (int j = 0; j < 8; j++)
                rr[j] = __builtin_nontemporal_load(recs + beg + k + j);
            uint2 hv[8];
            #pragma unroll
            for (int j = 0; j < 8; j++)
                hv[j] = hh2[(size_t)rr[j].x * D + lane];
            #pragma unroll
            for (int j = 0; j < 8; j += 2)
                edge_pair(rr[j], rr[j + 1], hv[j], hv[j + 1],
                          den0, den1, den2, den3, acc0, acc1, acc2, acc3);
        }
        if (k < dg) {  // clamped 8-wide final iteration (invalid edges w=0)
            i32x4 rr[8];
            #pragma unroll
            for (int j = 0; j < 8; j++) {
                int kk = min(k + j, dg - 1);
                i32x4 r = __builtin_nontemporal_load(recs + beg + kk);
                if (k + j >= dg) { r.z = 0; r.w = 0; }
                rr[j] = r;
            }
            uint2 hv[8];
            #pragma unroll
            for (int j = 0; j < 8; j++)
                hv[j] = hh2[(size_t)rr[j].x * D + lane];
            #pragma unroll
            for (int j = 0; j < 8; j += 2)
                edge_pair(rr[j], rr[j + 1], hv[j], hv[j + 1],
                          den0, den1, den2, den3, acc0, acc1, acc2, acc3);
        }

        float v = 0.25f * (acc0 / den0 + acc1 / den1 + acc2 / den2 + acc3 / den3);
        out[(size_t)i * D + lane] = v;
        sAcc = v;
        qAcc = v * v;
    }

    // block-level BN partial reduction (channel = lane)
    __shared__ float ls[256], lq[256];
    ls[t] = sAcc;
    lq[t] = qAcc;
    __syncthreads();
    if (t < 64) {
        float s = ls[t] + ls[t + 64] + ls[t + 128] + ls[t + 192];
        float q = lq[t] + lq[t + 64] + lq[t + 128] + lq[t + 192];
        const int sl = blockIdx.x & (BN_SLICES - 1);
        atomicAdd(&sums[sl * 128 + t], s);
        atomicAdd(&sums[sl * 128 + 64 + t], q);
    }
}

// BN apply: per-block LDS fold of the 32 slices into per-channel scale/
// shift, then float4-vectorized grid-stride stream over out (2048 blocks).
__global__ __launch_bounds__(256) void k_bn_apply(float* __restrict__ out,
                                                  const float* __restrict__ sums,
                                                  const float* __restrict__ gamma,
                                                  const float* __restrict__ beta,
                                                  int total, float invN) {
    __shared__ float red[128];
    __shared__ float scale_s[64], shift_s[64];
    const int t = threadIdx.x;
    if (t < 128) {
        float a = 0.f;
        #pragma unroll
        for (int sl = 0; sl < BN_SLICES; sl++) a += sums[sl * 128 + t];
        red[t] = a;     // t<64: channel sums; t in 64..127: channel sumsq
    }
    __syncthreads();
    if (t < 64) {
        float mean = red[t] * invN;
        float var = red[64 + t] * invN - mean * mean;
        float rs = rsqrtf(var + BN_EPS);
        float sc = gamma[t] * rs;
        scale_s[t] = sc;
        shift_s[t] = beta[t] - mean * sc;
    }
    __syncthreads();

    const int n4 = total >> 2;             // total % 4 == 0 (total = N*64)
    const int stride = gridDim.x * 256;
    for (int i4 = blockIdx.x * 256 + t; i4 < n4; i4 += stride) {
        float4 v = ((const float4*)out)[i4];
        const int c0 = (i4 << 2) & 63;
        v.x = fmaxf(v.x * scale_s[c0]     + shift_s[c0],     0.f);
        v.y = fmaxf(v.y * scale_s[c0 + 1] + shift_s[c0 + 1], 0.f);
        v.z = fmaxf(v.z * scale_s[c0 + 2] + shift_s[c0 + 2], 0.f);
        v.w = fmaxf(v.w * scale_s[c0 + 3] + shift_s[c0 + 3], 0.f);
        ((float4*)out)[i4] = v;
    }
}

extern "C" void kernel_launch(void* const* d_in, const int* in_sizes, int n_in,
                              void* d_out, int out_size, void* d_ws, size_t ws_size,
                              hipStream_t stream) {
    const float* x       = (const float*)d_in[0];
    const int*   ei      = (const int*)d_in[1];
    const float* W_lin   = (const float*)d_in[2];
    const float* b_lin   = (const float*)d_in[3];
    const float* prelu_w = (const float*)d_in[4];
    const float* W_gat   = (const float*)d_in[5];
    const float* att_src = (const float*)d_in[6];
    const float* att_dst = (const float*)d_in[7];
    // d_in[8] = gat_bias: constant per-channel shift cancelled exactly by BN
    // mean-subtraction -> skipped.
    const float* bn_gamma = (const float*)d_in[9];
    const float* bn_beta  = (const float*)d_in[10];
    float* out = (float*)d_out;

    const int N = in_sizes[0] / D;
    const int E = in_sizes[1] / 2;

    // sort geometry: 4 node groups, even-sized so packed u16 pairs never
    // straddle a group boundary. N=50000 -> NG=12500, Wg=6250, WTOT=25000.
    const int NG = 2 * ((N + 2 * NGROUPS - 1) / (2 * NGROUPS));
    const int WTOT = NGROUPS * (NG >> 1);

    // workspace carve-up (all chunk sizes multiples of 16B). No memset:
    // gcount zeroed by k_nodehist, sums zeroed by k_off (stream-ordered).
    char* wp = (char*)d_ws;
    _Float16* hh = (_Float16*)wp;      wp += (size_t)N * D * H * sizeof(_Float16);
    float* asrc  = (float*)wp;          wp += (size_t)N * H * sizeof(float);
    float* adst  = (float*)wp;          wp += (size_t)N * H * sizeof(float);
    float* sums  = (float*)wp;          wp += (size_t)BN_SLICES * 128 * sizeof(float);
    int* gcount  = (int*)wp;            wp += 4 * sizeof(int);
    _Float16* wlin_hi = (_Float16*)wp;  wp += (size_t)64 * 64 * sizeof(_Float16);
    _Float16* wlin_lo = (_Float16*)wp;  wp += (size_t)64 * 64 * sizeof(_Float16);
    _Float16* wgat_hi = (_Float16*)wp;  wp += (size_t)256 * 64 * sizeof(_Float16);
    _Float16* wgat_lo = (_Float16*)wp;  wp += (size_t)256 * 64 * sizeof(_Float16);
    int* offs    = (int*)wp;            wp += (size_t)((N + 3) & ~3) * sizeof(int);
    int* deg     = (int*)wp;            wp += (size_t)((N + 3) & ~3) * sizeof(int);
    int* rank    = (int*)wp;            wp += (size_t)((E + 3) & ~3) * sizeof(int);
    i32x4* recs  = (i32x4*)wp;          wp += (size_t)E * sizeof(i32x4);
    // gcnt (PSORT x WTOT u32 = 6.4 MB at N=50000) ALIASES d_out: its last
    // read is in k_fill, which stream-order completes before k_agg writes
    // out. Fallback to ws if out too small.
    unsigned int* gcnt;
    if ((size_t)PSORT * WTOT * sizeof(unsigned int) <= (size_t)out_size) {
        gcnt = (unsigned int*)d_out;
    } else {
        gcnt = (unsigned int*)wp;
        wp += (size_t)PSORT * WTOT * sizeof(unsigned int);
    }
    (void)ws_size; (void)n_in;

    const int total = N * D;
    const int NB1 = (N + 31) / 32;             // node-GEMM blocks
    const int NBH = NGROUPS * PSORT;           // hist blocks (scheduled FIRST)
    const int NBU = NBH + NB1;                 // unified grid
    const int NBO = (WTOT + 255) / 256;        // k_off grid (node pairs)
    const int NBA = (N + 3) / 4;               // k_agg grid (1 node/wave)

    hipLaunchKernelGGL(k_prep, dim3(64), dim3(256), 0, stream,
                       W_lin, W_gat, wlin_hi, wlin_lo, wgat_hi, wgat_lo);
    hipLaunchKernelGGL(k_nodehist, dim3(NBU), dim3(256), 0, stream,
                       x, wlin_hi, wlin_lo, b_lin, prelu_w, wgat_hi, wgat_lo,
                       att_src, att_dst, hh, asrc, adst, ei, gcnt, rank,
                       gcount, N, E, NBH, NG, WTOT);
    hipLaunchKernelGGL(k_off, dim3(NBO), dim3(256), 0, stream,
                       gcnt, gcount, offs, deg, sums, N, WTOT);
    hipLaunchKernelGGL(k_fill, dim3((E + 255) / 256), dim3(256), 0, stream,
                       ei, gcnt, offs, rank, asrc, adst, recs, E, WTOT);
    hipLaunchKernelGGL(k_agg, dim3(NBA), dim3(256), 0, stream,
                       asrc, adst, offs, deg, recs, (const uint2*)hh, out, sums, N);
    hipLaunchKernelGGL(k_bn_apply, dim3(2048), dim3(256), 0, stream,
                       out, sums, bn_gamma, bn_beta, total, 1.f / (float)N);
}

// Round 13
// 213.515 us; speedup vs baseline: 1.0138x; 1.0138x over previous
//
#include <hip/hip_runtime.h>
#include <hip/hip_fp16.h>

#define NEG_SLOPE 0.2f
#define BN_EPS 1e-5f

constexpr int D = 64;   // feature dim
constexpr int H = 4;    // heads

// ---- direct-CSR counting sort geometry ----
// Per-node u16 counters packed 2-per-u32 in LDS. Edge partitions are pow2
// chunks so p = e>>CHUNK_SHIFT (no div). Per-partition per-node count <=
// CHUNK = 16384 < 65536 -> no u16 carry.
constexpr int PSORT = 64;                  // edge partitions
constexpr int CHUNK_SHIFT = 14;            // 16384 edges/partition
constexpr int CHUNK = 1 << CHUNK_SHIFT;    // covers E <= 1,048,576
constexpr int NGROUPS = 4;                 // node groups (hist blocks per p)
constexpr int MAXWG = 6272;                // packed words per group -> N <= 50176
constexpr int BN_SLICES = 32;              // BN stat privatization

typedef _Float16 half2_t __attribute__((ext_vector_type(2)));
typedef _Float16 half4_t __attribute__((ext_vector_type(4)));
typedef _Float16 half8_t __attribute__((ext_vector_type(8)));
typedef float f32x4_t __attribute__((ext_vector_type(4)));
typedef int i32x4 __attribute__((ext_vector_type(4)));  // native vec for nontemporal builtins

// 16-B edge record: {src, pad, w[4]}; w = per-edge softmax numerators (4 heads)
union Rec {
    i32x4 i4;
    struct { int idx; int pad; half4_t w; } f;
};

#define MFMA16(a, b, c) __builtin_amdgcn_mfma_f32_16x16x32_f16(a, b, c, 0, 0, 0)

#if __has_builtin(__builtin_amdgcn_fdot2)
#define FDOT2(a, b, c) __builtin_amdgcn_fdot2((a), (b), (c), false)
#else
#define FDOT2(a, b, c) ((c) + (float)(a)[0] * (float)(b)[0] + (float)(a)[1] * (float)(b)[1])
#endif

__device__ inline half2_t h2cast(unsigned int u) { return __builtin_bit_cast(half2_t, u); }

__device__ inline float lrelu(float v) { return (v >= 0.f) ? v : NEG_SLOPE * v; }

// load 8 consecutive fp32, split into fp16 hi + lo halves (hi+lo ~ fp32)
__device__ inline void split8(const float* p, bool ok, half8_t& hi, half8_t& lo) {
    float f[8];
    if (ok) {
        float4 a = *(const float4*)p;
        float4 b = *(const float4*)(p + 4);
        f[0] = a.x; f[1] = a.y; f[2] = a.z; f[3] = a.w;
        f[4] = b.x; f[5] = b.y; f[6] = b.z; f[7] = b.w;
    } else {
        #pragma unroll
        for (int j = 0; j < 8; j++) f[j] = 0.f;
    }
    #pragma unroll
    for (int j = 0; j < 8; j++) {
        _Float16 h = (_Float16)f[j];
        hi[j] = h;
        lo[j] = (_Float16)(f[j] - (float)h);
    }
}

// UNIFIED node-GEMM + histogram kernel. Hist blocks FIRST (R11: 256 blocks
// at 1-2/CU co-reside with GEMM; GEMM-first serialized the roles).
// R13: REVERT of R12's weight pre-split (k_prep) — it regressed +2.5us:
// the GEMM role is not weight-VALU-bound (split8 hides under MFMA/VMEM at
// 6 blocks/CU) and the extra dispatch cost 2-4us. In-kernel split restored.
//   blocks [0, NBH):        per-(partition p, node-group g) packed-u16 LDS
//                           histogram; emits gcnt[p][*] + rank[e]; block 0
//                           zeroes gcount.
//   blocks [NBH, NBH+NB1):  32-node MFMA GEMM
__global__ __launch_bounds__(256) void k_nodehist(
    const float* __restrict__ x,
    const float* __restrict__ W_lin, const float* __restrict__ b_lin,
    const float* __restrict__ prelu_w, const float* __restrict__ W_gat,
    const float* __restrict__ att_src, const float* __restrict__ att_dst,
    _Float16* __restrict__ hh, float* __restrict__ asrc_ws,
    float* __restrict__ adst_ws, const int* __restrict__ ei,
    unsigned int* __restrict__ gcnt, int* __restrict__ rank,
    int* __restrict__ gcount, int N, int E, int NBH, int NG, int WTOT)
{
    __shared__ unsigned int smem4[MAXWG];  // 25.1 KB shared by both roles
    const int t = threadIdx.x;

    if ((int)blockIdx.x < NBH) {
        // ---------------- histogram role ----------------
        unsigned int* cnt = smem4;
        const int hb = blockIdx.x;
        const int p = hb & (PSORT - 1);
        const int g = hb >> 6;             // node group 0..3 (PSORT=64)
        const int Wg = NG >> 1;            // packed words per group
        for (int i = t; i < Wg; i += 256) cnt[i] = 0;
        __syncthreads();
        const int e0 = p << CHUNK_SHIFT;
        const int e1 = min(E, e0 + CHUNK);
        const int nlo = g * NG;
        for (int e = e0 + t; e < e1; e += 256) {
            int dl = ei[E + e] - nlo;
            if ((unsigned)dl < (unsigned)NG) {
                const unsigned int sh = (unsigned)(dl & 1) * 16;
                unsigned int old = atomicAdd(&cnt[dl >> 1], 1u << sh);
                rank[e] = (int)((old >> sh) & 0xffffu);
            }
        }
        __syncthreads();
        unsigned int* dst = gcnt + (size_t)p * WTOT + (size_t)g * Wg;
        for (int i = t; i < Wg; i += 256) dst[i] = cnt[i];
        if (hb == 0 && t == 0) gcount[0] = 0;   // stream-ordered before k_off
        return;
    }

    // ---------------- node GEMM role ----------------
    _Float16* smem = (_Float16*)smem4;
    _Float16* __restrict__ h_lds = smem;           // [32][264] after re-barrier
    _Float16* __restrict__ x1hi  = smem;           // [32][72]
    _Float16* __restrict__ x1lo  = smem + 32 * 72; // [32][72]

    const int w = t >> 6;    // wave id == head
    const int l = t & 63;
    const int li = l & 15;
    const int lq = l >> 4;
    const int base = (blockIdx.x - NBH) * 32;
    const int nvalid = min(32, N - base);

    // ---- stage A: MFMA x @ W_lin^T for cols 16w..16w+15, 2 m-tiles ----
    f32x4_t accA[2] = {};
    {
        half8_t blh[2], bll[2];
        const int n = 16 * w + li;
        #pragma unroll
        for (int ks = 0; ks < 2; ks++)
            split8(W_lin + n * 64 + 32 * ks + 8 * lq, true, blh[ks], bll[ks]);
        #pragma unroll
        for (int mt = 0; mt < 2; mt++) {
            const int row = base + 16 * mt + li;
            const bool ok = row < N;
            #pragma unroll
            for (int ks = 0; ks < 2; ks++) {
                half8_t ah, al;
                split8(x + (size_t)row * 64 + 32 * ks + 8 * lq, ok, ah, al);
                accA[mt] = MFMA16(ah, blh[ks], accA[mt]);
                accA[mt] = MFMA16(al, blh[ks], accA[mt]);
                accA[mt] = MFMA16(ah, bll[ks], accA[mt]);
            }
        }
    }

    // epilogue A: +bias, prelu, split to fp16 hi/lo in LDS
    {
        const int n = 16 * w + li;
        const float bl = b_lin[n];
        const float pw = prelu_w[n];
        #pragma unroll
        for (int mt = 0; mt < 2; mt++) {
            #pragma unroll
            for (int r = 0; r < 4; r++) {
                const int m = 16 * mt + lq * 4 + r;
                float v = accA[mt][r] + bl;
                v = (v >= 0.f) ? v : pw * v;
                _Float16 hi = (_Float16)v;
                x1hi[m * 72 + n] = hi;
                x1lo[m * 72 + n] = (_Float16)(v - (float)hi);
            }
        }
    }
    __syncthreads();

    // ---- stage B: MFMA x1 @ W_gat^T for cols 64w..64w+63, 2 m-tiles ----
    half8_t xah[2][2], xal[2][2];
    #pragma unroll
    for (int mt = 0; mt < 2; mt++) {
        #pragma unroll
        for (int ks = 0; ks < 2; ks++) {
            const int off = (16 * mt + li) * 72 + 32 * ks + 8 * lq;
            xah[mt][ks] = *(const half8_t*)(&x1hi[off]);
            xal[mt][ks] = *(const half8_t*)(&x1lo[off]);
        }
    }
    f32x4_t accB[2][4] = {};
    #pragma unroll
    for (int nt = 0; nt < 4; nt++) {
        half8_t wh[2], wl[2];
        const int c = 64 * w + 16 * nt + li;
        #pragma unroll
        for (int ks = 0; ks < 2; ks++)
            split8(W_gat + (size_t)c * 64 + 32 * ks + 8 * lq, true, wh[ks], wl[ks]);
        #pragma unroll
        for (int mt = 0; mt < 2; mt++) {
            #pragma unroll
            for (int ks = 0; ks < 2; ks++) {
                accB[mt][nt] = MFMA16(xah[mt][ks], wh[ks], accB[mt][nt]);
                accB[mt][nt] = MFMA16(xal[mt][ks], wh[ks], accB[mt][nt]);
                accB[mt][nt] = MFMA16(xah[mt][ks], wl[ks], accB[mt][nt]);
            }
        }
    }

    // ---- attention dots from registers: a[n][w] = sum_d h[n][w][d]*att[w][d]
    {
        float asv[4], adv[4];
        #pragma unroll
        for (int nt = 0; nt < 4; nt++) {
            const int c = 64 * w + 16 * nt + li;
            asv[nt] = att_src[c];
            adv[nt] = att_dst[c];
        }
        #pragma unroll
        for (int mt = 0; mt < 2; mt++) {
            #pragma unroll
            for (int r = 0; r < 4; r++) {
                float s = 0.f, dsum = 0.f;
                #pragma unroll
                for (int nt = 0; nt < 4; nt++) {
                    s += accB[mt][nt][r] * asv[nt];
                    dsum += accB[mt][nt][r] * adv[nt];
                }
                #pragma unroll
                for (int off = 1; off < 16; off <<= 1) {
                    s += __shfl_xor(s, off, 64);
                    dsum += __shfl_xor(dsum, off, 64);
                }
                if (li == 0) {
                    const int m = 16 * mt + lq * 4 + r;
                    if (m < nvalid) {
                        asrc_ws[(size_t)(base + m) * H + w] = s;
                        adst_ws[(size_t)(base + m) * H + w] = dsum;
                    }
                }
            }
        }
    }

    // WAR guard: all waves must finish their x1 ds_reads before h_lds
    // (same LDS bytes) is overwritten.
    __syncthreads();

    // ---- h -> LDS in padded [m][264] layout, then coalesced global write ----
    #pragma unroll
    for (int mt = 0; mt < 2; mt++) {
        #pragma unroll
        for (int nt = 0; nt < 4; nt++) {
            #pragma unroll
            for (int r = 0; r < 4; r++) {
                const int m = 16 * mt + lq * 4 + r;
                const int d = 16 * nt + li;
                h_lds[m * 264 + d * 4 + w] = (_Float16)accB[mt][nt][r];
            }
        }
    }
    __syncthreads();
    {
        const int chunks = nvalid * 32;  // 8 halves (16B) per chunk
        const uint4* src = (const uint4*)h_lds;
        uint4* dst = (uint4*)(hh + (size_t)base * 256);
        for (int i = t; i < chunks; i += 256) {
            int row = i >> 5;
            int col = i & 31;
            dst[i] = src[row * 33 + col];  // padded row = 33 uint4
        }
    }
}

// Pass 2: one thread per node PAIR, column-walk over the PSORT partials with
// 32-wide batched prefetch (R7: the serial walk was a ~45us latency chain).
// PSORT=64 -> 2 rounds. Block 0 also zeroes the BN sums slices.
__global__ __launch_bounds__(256) void k_off(unsigned int* __restrict__ gcnt,
                                             int* __restrict__ gcount,
                                             int* __restrict__ offs,
                                             int* __restrict__ deg,
                                             float* __restrict__ sums,
                                             int N, int WTOT) {
    if (blockIdx.x == 0) {
        for (int j = threadIdx.x; j < BN_SLICES * 128; j += 256) sums[j] = 0.f;
    }
    __shared__ int sm[256];
    __shared__ int sbase;
    const int t = threadIdx.x;
    const int i = blockIdx.x * 256 + t;      // pair index
    int d0 = 0, d1 = 0;
    if (i < WTOT) {
        unsigned int run = 0;                // packed running prefix
        for (int pb = 0; pb < PSORT; pb += 32) {
            unsigned int c[32];
            #pragma unroll
            for (int j = 0; j < 32; j++)
                c[j] = gcnt[(size_t)(pb + j) * WTOT + i];
            #pragma unroll
            for (int j = 0; j < 32; j++) {
                unsigned int cc = c[j];
                gcnt[(size_t)(pb + j) * WTOT + i] = run;
                run += cc;
            }
        }
        d0 = (int)(run & 0xffffu);
        d1 = (int)(run >> 16);
    }
    int v = d0 + d1;
    sm[t] = v;
    __syncthreads();
    for (int off = 1; off < 256; off <<= 1) {
        int u = (t >= off) ? sm[t - off] : 0;
        __syncthreads();
        sm[t] += u;
        __syncthreads();
    }
    if (t == 255) sbase = atomicAdd(gcount, sm[255]);
    __syncthreads();
    const int base = sbase + sm[t] - v;
    const int n0 = 2 * i;
    if (n0 < N)     { offs[n0] = base;          deg[n0] = d0; }
    if (n0 + 1 < N) { offs[n0 + 1] = base + d0; deg[n0 + 1] = d1; }
}

// Pass 3: single full-occupancy per-edge pass:
// pos = offs[d] + pref[p][d] + rank[e]; one NT 16-B store per rec.
__global__ __launch_bounds__(256) void k_fill(const int* __restrict__ ei,
                                              const unsigned int* __restrict__ gcnt,
                                              const int* __restrict__ offs,
                                              const int* __restrict__ rank,
                                              const float* __restrict__ asrc,
                                              const float* __restrict__ adst,
                                              i32x4* __restrict__ recs,
                                              int E, int WTOT) {
    int e = blockIdx.x * 256 + threadIdx.x;
    if (e >= E) return;
    int s = ei[e];
    int d = ei[E + e];
    int p = e >> CHUNK_SHIFT;
    const unsigned int sh = (unsigned)(d & 1) * 16;
    int pr = (int)((gcnt[(size_t)p * WTOT + (d >> 1)] >> sh) & 0xffffu);
    int pos = offs[d] + pr + rank[e];
    float4 a = *(const float4*)(asrc + (size_t)s * H);
    float4 b = *(const float4*)(adst + (size_t)d * H);
    Rec r;
    r.f.idx = s;
    r.f.pad = 0;
    r.f.w[0] = (_Float16)__expf(lrelu(a.x + b.x));
    r.f.w[1] = (_Float16)__expf(lrelu(a.y + b.y));
    r.f.w[2] = (_Float16)__expf(lrelu(a.z + b.z));
    r.f.w[3] = (_Float16)__expf(lrelu(a.w + b.w));
    __builtin_nontemporal_store(r.i4, recs + pos);
}

// process one edge pair (A,B) with packed fp16 math.
__device__ inline void edge_pair(const i32x4 ra, const i32x4 rb,
                                 const uint2 ha, const uint2 hb,
                                 float& den0, float& den1, float& den2, float& den3,
                                 float& acc0, float& acc1, float& acc2, float& acc3)
{
    const half2_t one2 = h2cast(0x3C003C00u);
    unsigned int wp0 = __builtin_amdgcn_perm((unsigned int)rb.z, (unsigned int)ra.z, 0x05040100u);
    unsigned int wp1 = __builtin_amdgcn_perm((unsigned int)rb.z, (unsigned int)ra.z, 0x07060302u);
    unsigned int wp2 = __builtin_amdgcn_perm((unsigned int)rb.w, (unsigned int)ra.w, 0x05040100u);
    unsigned int wp3 = __builtin_amdgcn_perm((unsigned int)rb.w, (unsigned int)ra.w, 0x07060302u);
    unsigned int hp0 = __builtin_amdgcn_perm(hb.x, ha.x, 0x05040100u);
    unsigned int hp1 = __builtin_amdgcn_perm(hb.x, ha.x, 0x07060302u);
    unsigned int hp2 = __builtin_amdgcn_perm(hb.y, ha.y, 0x05040100u);
    unsigned int hp3 = __builtin_amdgcn_perm(hb.y, ha.y, 0x07060302u);
    den0 = FDOT2(h2cast(wp0), one2, den0);
    den1 = FDOT2(h2cast(wp1), one2, den1);
    den2 = FDOT2(h2cast(wp2), one2, den2);
    den3 = FDOT2(h2cast(wp3), one2, den3);
    acc0 = FDOT2(h2cast(wp0), h2cast(hp0), acc0);
    acc1 = FDOT2(h2cast(wp1), h2cast(hp1), acc1);
    acc2 = FDOT2(h2cast(wp2), h2cast(hp2), acc2);
    acc3 = FDOT2(h2cast(wp3), h2cast(hp3), acc3);
}

// ---- fused softmax + aggregation + BN partial stats ----
// One node per wave (R9 geometry: 12500 blocks, occupancy ~70%, ~59.5us —
// at the random-gather fabric floor; FETCH 198MB ~ 8 XCD x hh re-fetch).
// BN: block-level LDS reduction then 128 atomics/block onto 32-way-sliced
// sums. Barrier-safe: invalid waves contribute zeros.
__global__ __launch_bounds__(256) void k_agg(
    const float* __restrict__ asrc, const float* __restrict__ adst,
    const int* __restrict__ offs, const int* __restrict__ deg,
    const i32x4* __restrict__ recs, const uint2* __restrict__ hh2,
    float* __restrict__ out, float* __restrict__ sums, int N)
{
    const int t = threadIdx.x;
    const int w = t >> 6;
    const int lane = t & 63;
    const int i = blockIdx.x * 4 + w;      // one node per wave

    float sAcc = 0.f, qAcc = 0.f;
    if (i < N) {
        float4 b = *(const float4*)(adst + (size_t)i * H);
        float4 a0 = *(const float4*)(asrc + (size_t)i * H);
        float ws0 = __expf(lrelu(a0.x + b.x));
        float ws1 = __expf(lrelu(a0.y + b.y));
        float ws2 = __expf(lrelu(a0.z + b.z));
        float ws3 = __expf(lrelu(a0.w + b.w));

        const int beg = __builtin_amdgcn_readfirstlane(offs[i]);
        const int dg  = __builtin_amdgcn_readfirstlane(deg[i]);

        // self-loop contribution
        float den0 = ws0, den1 = ws1, den2 = ws2, den3 = ws3;
        float acc0, acc1, acc2, acc3;
        {
            uint2 hv = hh2[(size_t)i * D + lane];
            half2_t s01 = h2cast(hv.x), s23 = h2cast(hv.y);
            acc0 = ws0 * (float)s01[0];
            acc1 = ws1 * (float)s01[1];
            acc2 = ws2 * (float)s23[0];
            acc3 = ws3 * (float)s23[1];
        }

        const int nfull = dg & ~7;
        int k = 0;
        for (; k < nfull; k += 8) {
            i32x4 rr[8];
            #pragma unroll
            for (int j = 0; j < 8; j++)
                rr[j] = __builtin_nontemporal_load(recs + beg + k + j);
            uint2 hv[8];
            #pragma unroll
            for (int j = 0; j < 8; j++)
                hv[j] = hh2[(size_t)rr[j].x * D + lane];
            #pragma unroll
            for (int j = 0; j < 8; j += 2)
                edge_pair(rr[j], rr[j + 1], hv[j], hv[j + 1],
                          den0, den1, den2, den3, acc0, acc1, acc2, acc3);
        }
        if (k < dg) {  // clamped 8-wide final iteration (invalid edges w=0)
            i32x4 rr[8];
            #pragma unroll
            for (int j = 0; j < 8; j++) {
                int kk = min(k + j, dg - 1);
                i32x4 r = __builtin_nontemporal_load(recs + beg + kk);
                if (k + j >= dg) { r.z = 0; r.w = 0; }
                rr[j] = r;
            }
            uint2 hv[8];
            #pragma unroll
            for (int j = 0; j < 8; j++)
                hv[j] = hh2[(size_t)rr[j].x * D + lane];
            #pragma unroll
            for (int j = 0; j < 8; j += 2)
                edge_pair(rr[j], rr[j + 1], hv[j], hv[j + 1],
                          den0, den1, den2, den3, acc0, acc1, acc2, acc3);
        }

        float v = 0.25f * (acc0 / den0 + acc1 / den1 + acc2 / den2 + acc3 / den3);
        out[(size_t)i * D + lane] = v;
        sAcc = v;
        qAcc = v * v;
    }

    // block-level BN partial reduction (channel = lane)
    __shared__ float ls[256], lq[256];
    ls[t] = sAcc;
    lq[t] = qAcc;
    __syncthreads();
    if (t < 64) {
        float s = ls[t] + ls[t + 64] + ls[t + 128] + ls[t + 192];
        float q = lq[t] + lq[t + 64] + lq[t + 128] + lq[t + 192];
        const int sl = blockIdx.x & (BN_SLICES - 1);
        atomicAdd(&sums[sl * 128 + t], s);
        atomicAdd(&sums[sl * 128 + 64 + t], q);
    }
}

// BN apply: per-block LDS fold of the 32 slices into per-channel scale/
// shift, then float4-vectorized grid-stride stream over out (2048 blocks).
__global__ __launch_bounds__(256) void k_bn_apply(float* __restrict__ out,
                                                  const float* __restrict__ sums,
                                                  const float* __restrict__ gamma,
                                                  const float* __restrict__ beta,
                                                  int total, float invN) {
    __shared__ float red[128];
    __shared__ float scale_s[64], shift_s[64];
    const int t = threadIdx.x;
    if (t < 128) {
        float a = 0.f;
        #pragma unroll
        for (int sl = 0; sl < BN_SLICES; sl++) a += sums[sl * 128 + t];
        red[t] = a;     // t<64: channel sums; t in 64..127: channel sumsq
    }
    __syncthreads();
    if (t < 64) {
        float mean = red[t] * invN;
        float var = red[64 + t] * invN - mean * mean;
        float rs = rsqrtf(var + BN_EPS);
        float sc = gamma[t] * rs;
        scale_s[t] = sc;
        shift_s[t] = beta[t] - mean * sc;
    }
    __syncthreads();

    const int n4 = total >> 2;             // total % 4 == 0 (total = N*64)
    const int stride = gridDim.x * 256;
    for (int i4 = blockIdx.x * 256 + t; i4 < n4; i4 += stride) {
        float4 v = ((const float4*)out)[i4];
        const int c0 = (i4 << 2) & 63;
        v.x = fmaxf(v.x * scale_s[c0]     + shift_s[c0],     0.f);
        v.y = fmaxf(v.y * scale_s[c0 + 1] + shift_s[c0 + 1], 0.f);
        v.z = fmaxf(v.z * scale_s[c0 + 2] + shift_s[c0 + 2], 0.f);
        v.w = fmaxf(v.w * scale_s[c0 + 3] + shift_s[c0 + 3], 0.f);
        ((float4*)out)[i4] = v;
    }
}

extern "C" void kernel_launch(void* const* d_in, const int* in_sizes, int n_in,
                              void* d_out, int out_size, void* d_ws, size_t ws_size,
                              hipStream_t stream) {
    const float* x       = (const float*)d_in[0];
    const int*   ei      = (const int*)d_in[1];
    const float* W_lin   = (const float*)d_in[2];
    const float* b_lin   = (const float*)d_in[3];
    const float* prelu_w = (const float*)d_in[4];
    const float* W_gat   = (const float*)d_in[5];
    const float* att_src = (const float*)d_in[6];
    const float* att_dst = (const float*)d_in[7];
    // d_in[8] = gat_bias: constant per-channel shift cancelled exactly by BN
    // mean-subtraction -> skipped.
    const float* bn_gamma = (const float*)d_in[9];
    const float* bn_beta  = (const float*)d_in[10];
    float* out = (float*)d_out;

    const int N = in_sizes[0] / D;
    const int E = in_sizes[1] / 2;

    // sort geometry: 4 node groups, even-sized so packed u16 pairs never
    // straddle a group boundary. N=50000 -> NG=12500, Wg=6250, WTOT=25000.
    const int NG = 2 * ((N + 2 * NGROUPS - 1) / (2 * NGROUPS));
    const int WTOT = NGROUPS * (NG >> 1);

    // workspace carve-up (all chunk sizes multiples of 16B). No memset:
    // gcount zeroed by k_nodehist, sums zeroed by k_off (stream-ordered).
    char* wp = (char*)d_ws;
    _Float16* hh = (_Float16*)wp;      wp += (size_t)N * D * H * sizeof(_Float16);
    float* asrc  = (float*)wp;          wp += (size_t)N * H * sizeof(float);
    float* adst  = (float*)wp;          wp += (size_t)N * H * sizeof(float);
    float* sums  = (float*)wp;          wp += (size_t)BN_SLICES * 128 * sizeof(float);
    int* gcount  = (int*)wp;            wp += 4 * sizeof(int);
    int* offs    = (int*)wp;            wp += (size_t)((N + 3) & ~3) * sizeof(int);
    int* deg     = (int*)wp;            wp += (size_t)((N + 3) & ~3) * sizeof(int);
    int* rank    = (int*)wp;            wp += (size_t)((E + 3) & ~3) * sizeof(int);
    i32x4* recs  = (i32x4*)wp;          wp += (size_t)E * sizeof(i32x4);
    // gcnt (PSORT x WTOT u32 = 6.4 MB at N=50000) ALIASES d_out: its last
    // read is in k_fill, which stream-order completes before k_agg writes
    // out. Fallback to ws if out too small.
    unsigned int* gcnt;
    if ((size_t)PSORT * WTOT * sizeof(unsigned int) <= (size_t)out_size) {
        gcnt = (unsigned int*)d_out;
    } else {
        gcnt = (unsigned int*)wp;
        wp += (size_t)PSORT * WTOT * sizeof(unsigned int);
    }
    (void)ws_size; (void)n_in;

    const int total = N * D;
    const int NB1 = (N + 31) / 32;             // node-GEMM blocks
    const int NBH = NGROUPS * PSORT;           // hist blocks (scheduled FIRST)
    const int NBU = NBH + NB1;                 // unified grid
    const int NBO = (WTOT + 255) / 256;        // k_off grid (node pairs)
    const int NBA = (N + 3) / 4;               // k_agg grid (1 node/wave)

    hipLaunchKernelGGL(k_nodehist, dim3(NBU), dim3(256), 0, stream,
                       x, W_lin, b_lin, prelu_w, W_gat, att_src, att_dst,
                       hh, asrc, adst, ei, gcnt, rank, gcount, N, E, NBH, NG, WTOT);
    hipLaunchKernelGGL(k_off, dim3(NBO), dim3(256), 0, stream,
                       gcnt, gcount, offs, deg, sums, N, WTOT);
    hipLaunchKernelGGL(k_fill, dim3((E + 255) / 256), dim3(256), 0, stream,
                       ei, gcnt, offs, rank, asrc, adst, recs, E, WTOT);
    hipLaunchKernelGGL(k_agg, dim3(NBA), dim3(256), 0, stream,
                       asrc, adst, offs, deg, recs, (const uint2*)hh, out, sums, N);
    hipLaunchKernelGGL(k_bn_apply, dim3(2048), dim3(256), 0, stream,
                       out, sums, bn_gamma, bn_beta, total, 1.f / (float)N);
}